// Round 6
// baseline (154.817 us; speedup 1.0000x reference)
//
#include <hip/hip_runtime.h>
#include <hip/hip_bf16.h>
#include <math.h>

#define Bc 2
#define Nn 2048
#define Hh 256
#define NH 8
#define Dd 32
#define WIN 32
#define WL 65
#define BN (Bc * Nn)   // 4096

typedef __attribute__((ext_vector_type(8))) short bf16x8;
typedef __attribute__((ext_vector_type(4))) float f32x4;

__device__ inline short f2bf(float f) {
    union { float f; unsigned u; } v; v.f = f;
    unsigned r = v.u + 0x7fffu + ((v.u >> 16) & 1u);
    return (short)(r >> 16);
}

// packed fp32 -> bf16 (RTNE, v_cvt_pk_bf16_f32 on gfx950)
__device__ inline bf16x8 cvt8(float4 a, float4 b) {
    union { __hip_bfloat162 h[4]; bf16x8 v; } u;
    u.h[0] = __float22bfloat162_rn(make_float2(a.x, a.y));
    u.h[1] = __float22bfloat162_rn(make_float2(a.z, a.w));
    u.h[2] = __float22bfloat162_rn(make_float2(b.x, b.y));
    u.h[3] = __float22bfloat162_rn(make_float2(b.z, b.w));
    return u.v;
}

// ---------------- cast + transpose weights -> bf16 B^T (N x K) ----------------
__global__ __launch_bounds__(256) void castw_kernel(
    const float* __restrict__ Wq, const float* __restrict__ Wk, const float* __restrict__ Wv,
    const float* __restrict__ Wvec, const float* __restrict__ Wg, const float* __restrict__ Wo,
    short* __restrict__ WqkvT, short* __restrict__ WvecT,
    short* __restrict__ WgT, short* __restrict__ WoT) {
    __shared__ float Ts[32][33];
    const int t = threadIdx.x;
    const int cc = t & 31, r0 = t >> 5;
    const int id = blockIdx.x;
    const float* W; int ldw; short* WT; int ldwt; int n0s, k0, n0d;
    if (id < 192) {            // [Wq|Wk|Wv] 256x768 -> WqkvT 768x256
        const int tn = id >> 3, tk = id & 7, sel = tn >> 3;
        W = sel == 0 ? Wq : (sel == 1 ? Wk : Wv); ldw = 256;
        n0s = (tn & 7) * 32; k0 = tk * 32; WT = WqkvT; ldwt = 256; n0d = tn * 32;
    } else if (id < 320) {     // Wvec 256x512 -> WvecT 512x256
        const int id2 = id - 192, tn = id2 >> 3, tk = id2 & 7;
        W = Wvec; ldw = 512; n0s = tn * 32; k0 = tk * 32; WT = WvecT; ldwt = 256; n0d = n0s;
    } else if (id < 448) {     // Wg 512x256 -> WgT 256x512
        const int id3 = id - 320, tn = id3 >> 4, tk = id3 & 15;
        W = Wg; ldw = 256; n0s = tn * 32; k0 = tk * 32; WT = WgT; ldwt = 512; n0d = n0s;
    } else {                   // Wo 256x768 -> WoT 768x256
        const int id4 = id - 448, tn = id4 >> 3, tk = id4 & 7;
        W = Wo; ldw = 768; n0s = tn * 32; k0 = tk * 32; WT = WoT; ldwt = 256; n0d = n0s;
    }
#pragma unroll
    for (int p = 0; p < 4; ++p) {
        const int rr = r0 + p * 8;
        Ts[rr][cc] = W[(size_t)(k0 + rr) * ldw + n0s + cc];
    }
    __syncthreads();
#pragma unroll
    for (int p = 0; p < 4; ++p) {
        const int rr = r0 + p * 8;
        WT[(size_t)(n0d + rr) * ldwt + k0 + cc] = f2bf(Ts[cc][rr]);
    }
}

// ---------------- fused mid kernel ----------------
// blocks [0,384): qkv GEMM (64 x 128 tiles, A from fp32 x inline)
// blocks [384,640): vecdotgate (16 rows: vec_proj + vec_dot + norm + gate)
__global__ __launch_bounds__(256) void fused_mid(
    const float* __restrict__ x,
    const short* __restrict__ WqkvT, const short* __restrict__ WvecT,
    const short* __restrict__ WgT,
    const float* __restrict__ bq, const float* __restrict__ bk, const float* __restrict__ bv,
    const float* __restrict__ alpha_dot, const float* __restrict__ alpha_norm,
    const float* __restrict__ bg,
    short* __restrict__ Qb, short* __restrict__ Kb, short* __restrict__ Vb,
    float* __restrict__ vec_dot, float* __restrict__ vec_norm, float* __restrict__ gate) {
    __shared__ __align__(16) short lds[31232];  // 62.5 KB
    const int bid = blockIdx.x;
    const int t = threadIdx.x, lane = t & 63, wid = t >> 6;
    const int quad = lane >> 4, lm = lane & 15;

    if (bid < 384) {
        // ---------------- qkv path ----------------
        short* As = lds;              // 64*40
        short* Bs = lds + 2560;       // 128*40
        const int rb = bid & 63, cb = bid >> 6;
        const int row0 = rb * 64, col0 = cb * 128;
        const int wm = wid & 1, wn = wid >> 1;
        const int srow = t >> 2, scg = (t & 3) * 8;
        f32x4 acc[2][4];
#pragma unroll
        for (int mt = 0; mt < 2; ++mt)
#pragma unroll
            for (int nt = 0; nt < 4; ++nt) {
                f32x4 z = {0.f, 0.f, 0.f, 0.f};
                acc[mt][nt] = z;
            }
        float4 pa0 = *(const float4*)&x[(size_t)(row0 + srow) * 1024 + scg];
        float4 pa1 = *(const float4*)&x[(size_t)(row0 + srow) * 1024 + scg + 4];
        bf16x8 pb[2];
#pragma unroll
        for (int p = 0; p < 2; ++p) {
            const int idx = t + p * 256;
            pb[p] = *(const bf16x8*)&WqkvT[(size_t)(col0 + (idx >> 2)) * 256 + (idx & 3) * 8];
        }
        for (int k0 = 0; k0 < 256; k0 += 32) {
            *(bf16x8*)&As[srow * 40 + scg] = cvt8(pa0, pa1);
#pragma unroll
            for (int p = 0; p < 2; ++p) {
                const int idx = t + p * 256;
                *(bf16x8*)&Bs[(idx >> 2) * 40 + (idx & 3) * 8] = pb[p];
            }
            __syncthreads();
            if (k0 + 32 < 256) {
                pa0 = *(const float4*)&x[(size_t)(row0 + srow) * 1024 + k0 + 32 + scg];
                pa1 = *(const float4*)&x[(size_t)(row0 + srow) * 1024 + k0 + 32 + scg + 4];
#pragma unroll
                for (int p = 0; p < 2; ++p) {
                    const int idx = t + p * 256;
                    pb[p] = *(const bf16x8*)&WqkvT[(size_t)(col0 + (idx >> 2)) * 256 + k0 + 32 + (idx & 3) * 8];
                }
            }
            bf16x8 af[2], bfr[4];
#pragma unroll
            for (int mt = 0; mt < 2; ++mt)
                af[mt] = *(bf16x8*)&As[(wm * 32 + mt * 16 + lm) * 40 + quad * 8];
#pragma unroll
            for (int nt = 0; nt < 4; ++nt)
                bfr[nt] = *(bf16x8*)&Bs[(wn * 64 + nt * 16 + lm) * 40 + quad * 8];
#pragma unroll
            for (int mt = 0; mt < 2; ++mt)
#pragma unroll
                for (int nt = 0; nt < 4; ++nt)
                    acc[mt][nt] = __builtin_amdgcn_mfma_f32_16x16x32_bf16(
                        af[mt], bfr[nt], acc[mt][nt], 0, 0, 0);
            __syncthreads();
        }
        const int chunk = col0 >> 8;
        short* dst = chunk == 0 ? Qb : (chunk == 1 ? Kb : Vb);
        const float* bias = chunk == 0 ? bq : (chunk == 1 ? bk : bv);
#pragma unroll
        for (int mt = 0; mt < 2; ++mt)
#pragma unroll
            for (int nt = 0; nt < 4; ++nt) {
                const int col = col0 + (wid >> 1) * 64 + nt * 16 + lm;
                const int cm = col & 255;
                const float bb = bias[cm];
#pragma unroll
                for (int r = 0; r < 4; ++r) {
                    const int row = row0 + (wid & 1) * 32 + mt * 16 + quad * 4 + r;
                    dst[(size_t)row * 256 + cm] = f2bf(acc[mt][nt][r] + bb);
                }
            }
        return;
    }

    // ---------------- vecdotgate path ----------------
    short* As    = lds;            // 3 planes x 16 rows x 264 = 12672
    short* Bs    = lds + 12672;    // 10240 (2x128x40 or flat 256x40)
    short* inv_s = lds + 22912;    // 16 rows x 520 = 8320
    const int row0 = (bid - 384) * 16;

    // Phase A: stage A (bf16) + fp32 norms
#pragma unroll
    for (int it = 0; it < 6; ++it) {
        const int idx = t + it * 256;          // [0,1536)
        const int p = idx >> 9, rem = idx & 511, row = rem >> 5, kg = rem & 31;
        const float* src = &x[(size_t)(row0 + row) * 1024 + (1 + p) * 256 + kg * 8];
        *(bf16x8*)&As[(p * 16 + row) * 264 + kg * 8] =
            cvt8(*(const float4*)src, *(const float4*)(src + 4));
    }
    const float an = alpha_norm[0], ad = alpha_dot[0];
#pragma unroll
    for (int it = 0; it < 4; ++it) {
        const int idx = t + it * 256;          // [0,1024)
        const int row = idx >> 6, c4 = idx & 63;
        const size_t xb = (size_t)(row0 + row) * 1024 + c4 * 4;
        const float4 v0 = *(const float4*)&x[xb + 256];
        const float4 v1 = *(const float4*)&x[xb + 512];
        const float4 v2 = *(const float4*)&x[xb + 768];
        float4 nr;
        nr.x = sqrtf(v0.x * v0.x + v1.x * v1.x + v2.x * v2.x);
        nr.y = sqrtf(v0.y * v0.y + v1.y * v1.y + v2.y * v2.y);
        nr.z = sqrtf(v0.z * v0.z + v1.z * v1.z + v2.z * v2.z);
        nr.w = sqrtf(v0.w * v0.w + v1.w * v1.w + v2.w * v2.w);
        *(float4*)&vec_norm[(size_t)(row0 + row) * 256 + c4 * 4] = nr;
        short* ip = &inv_s[row * 520 + 256 + c4 * 4];
        ip[0] = f2bf(an * nr.x); ip[1] = f2bf(an * nr.y);
        ip[2] = f2bf(an * nr.z); ip[3] = f2bf(an * nr.w);
    }
    __syncthreads();

    // Phase B: vec_proj (2 col-groups of 128) + dot -> inv_s
    for (int cg = 0; cg < 2; ++cg) {
        f32x4 acc[3][2][2];
#pragma unroll
        for (int p = 0; p < 3; ++p)
#pragma unroll
            for (int h = 0; h < 2; ++h)
#pragma unroll
                for (int nt = 0; nt < 2; ++nt) {
                    f32x4 z = {0.f, 0.f, 0.f, 0.f};
                    acc[p][h][nt] = z;
                }
        bf16x8 pb[4];
#pragma unroll
        for (int q = 0; q < 4; ++q) {
            const int idx = t + q * 256;       // [0,1024)
            const int h = idx >> 9, rem = idx & 511, col = rem >> 2, kg = rem & 3;
            pb[q] = *(const bf16x8*)&WvecT[(size_t)(h * 256 + cg * 128 + col) * 256 + kg * 8];
        }
        for (int k0 = 0; k0 < 256; k0 += 32) {
#pragma unroll
            for (int q = 0; q < 4; ++q) {
                const int idx = t + q * 256;
                const int h = idx >> 9, rem = idx & 511, col = rem >> 2, kg = rem & 3;
                *(bf16x8*)&Bs[(h * 128 + col) * 40 + kg * 8] = pb[q];
            }
            __syncthreads();
            if (k0 + 32 < 256) {
#pragma unroll
                for (int q = 0; q < 4; ++q) {
                    const int idx = t + q * 256;
                    const int h = idx >> 9, rem = idx & 511, col = rem >> 2, kg = rem & 3;
                    pb[q] = *(const bf16x8*)&WvecT[(size_t)(h * 256 + cg * 128 + col) * 256 + k0 + 32 + kg * 8];
                }
            }
            bf16x8 af[3], bfr[2][2];
#pragma unroll
            for (int p = 0; p < 3; ++p)
                af[p] = *(bf16x8*)&As[(p * 16 + lm) * 264 + k0 + quad * 8];
#pragma unroll
            for (int h = 0; h < 2; ++h)
#pragma unroll
                for (int nt = 0; nt < 2; ++nt)
                    bfr[h][nt] = *(bf16x8*)&Bs[(h * 128 + wid * 32 + nt * 16 + lm) * 40 + quad * 8];
#pragma unroll
            for (int p = 0; p < 3; ++p)
#pragma unroll
                for (int h = 0; h < 2; ++h)
#pragma unroll
                    for (int nt = 0; nt < 2; ++nt)
                        acc[p][h][nt] = __builtin_amdgcn_mfma_f32_16x16x32_bf16(
                            af[p], bfr[h][nt], acc[p][h][nt], 0, 0, 0);
            __syncthreads();
        }
#pragma unroll
        for (int nt = 0; nt < 2; ++nt) {
            const int col = cg * 128 + wid * 32 + nt * 16 + lm;
#pragma unroll
            for (int r = 0; r < 4; ++r) {
                const int row = quad * 4 + r;
                float dot = 0.f;
#pragma unroll
                for (int p = 0; p < 3; ++p)
                    dot = fmaf(acc[p][0][nt][r], acc[p][1][nt][r], dot);
                vec_dot[(size_t)(row0 + row) * 256 + col] = dot;
                inv_s[row * 520 + col] = f2bf(ad * dot);
            }
        }
        __syncthreads();
    }

    // Phase C: gate = sigmoid(inv @ Wg + bg), 16 x 256, K=512
    f32x4 g[4];
#pragma unroll
    for (int nt = 0; nt < 4; ++nt) {
        f32x4 z = {0.f, 0.f, 0.f, 0.f};
        g[nt] = z;
    }
    bf16x8 pg[4];
#pragma unroll
    for (int q = 0; q < 4; ++q) {
        const int idx = t + q * 256;           // [0,1024)
        pg[q] = *(const bf16x8*)&WgT[(size_t)(idx >> 2) * 512 + (idx & 3) * 8];
    }
    for (int k0 = 0; k0 < 512; k0 += 32) {
#pragma unroll
        for (int q = 0; q < 4; ++q) {
            const int idx = t + q * 256;
            *(bf16x8*)&Bs[(idx >> 2) * 40 + (idx & 3) * 8] = pg[q];
        }
        __syncthreads();
        if (k0 + 32 < 512) {
#pragma unroll
            for (int q = 0; q < 4; ++q) {
                const int idx = t + q * 256;
                pg[q] = *(const bf16x8*)&WgT[(size_t)(idx >> 2) * 512 + k0 + 32 + (idx & 3) * 8];
            }
        }
        const bf16x8 ai = *(bf16x8*)&inv_s[lm * 520 + k0 + quad * 8];
#pragma unroll
        for (int nt = 0; nt < 4; ++nt) {
            const bf16x8 bgf = *(bf16x8*)&Bs[(wid * 64 + nt * 16 + lm) * 40 + quad * 8];
            g[nt] = __builtin_amdgcn_mfma_f32_16x16x32_bf16(ai, bgf, g[nt], 0, 0, 0);
        }
        __syncthreads();
    }
#pragma unroll
    for (int nt = 0; nt < 4; ++nt) {
        const int col = wid * 64 + nt * 16 + lm;
        const float bb = bg[col];
#pragma unroll
        for (int r = 0; r < 4; ++r) {
            const int row = row0 + quad * 4 + r;
            const float z = g[nt][r] + bb;
            gate[(size_t)row * 256 + col] = 1.f / (1.f + __expf(-z));
        }
    }
}

// ---------------- fused attention: wave-split scores/staging overlap ----------------
__global__ __launch_bounds__(256) void attn_fused(
    const short* __restrict__ Qb, const short* __restrict__ Kb,
    const short* __restrict__ Vb,
    const float* __restrict__ gate, const float* __restrict__ x,
    float* __restrict__ attnw, float* __restrict__ out, short* __restrict__ xout_bf) {
    const int bh = blockIdx.x >> 6, tile = blockIdx.x & 63;
    const int b = bh >> 3, hd = bh & 7;
    const int i0 = tile * 32;
    const int t = threadIdx.x, lane = t & 63, wid = t >> 6;
    const int wm = wid & 1, wn = wid >> 1, quad = lane >> 4, lm = lane & 15;

    __shared__ __align__(16) short Qs[32 * 40];    // i, d
    __shared__ __align__(16) short Ks[96 * 40];    // j, d (OOB rows = 0)
    __shared__ __align__(16) short Pb[32 * 104];   // i, jr bf16 weights (band, else 0)
    __shared__ __align__(16) short St[128 * 104];  // dim, jr (S transposed)

    // phase 1: zero Pb; stage Q + K
    for (int idx = t; idx < 32 * 104 / 2; idx += 256) ((int*)Pb)[idx] = 0;
    if (t < 128) {
        const int row = t >> 2, cg = t & 3;
        *(bf16x8*)&Qs[row * 40 + cg * 8] =
            *(const bf16x8*)&Qb[((size_t)(b * Nn + i0 + row)) * 256 + hd * 32 + cg * 8];
    }
#pragma unroll
    for (int kk = 0; kk < 2; ++kk) {
        const int idx = t + kk * 256;
        if (idx < 384) {
            const int row = idx >> 2, cg = idx & 3;
            const int j = i0 - WIN + row;
            bf16x8 kv = {0, 0, 0, 0, 0, 0, 0, 0};
            if (j >= 0 && j < Nn)
                kv = *(const bf16x8*)&Kb[((size_t)(b * Nn + j)) * 256 + hd * 32 + cg * 8];
            *(bf16x8*)&Ks[row * 40 + cg * 8] = kv;
        }
    }
    __syncthreads();

    // phase 2: waves 0-1 scores+softmax; waves 2-3 stage S^T
    if (wid < 2) {
        const int il0 = wid * 16;
        const bf16x8 aq = *(bf16x8*)&Qs[(il0 + lm) * 40 + quad * 8];
        f32x4 c[6];
#pragma unroll
        for (int nt = 0; nt < 6; ++nt) {
            const bf16x8 bk = *(bf16x8*)&Ks[(nt * 16 + lm) * 40 + quad * 8];
            f32x4 z = {0.f, 0.f, 0.f, 0.f};
            c[nt] = __builtin_amdgcn_mfma_f32_16x16x32_bf16(aq, bk, z, 0, 0, 0);
        }
        float mx[4] = {-1e30f, -1e30f, -1e30f, -1e30f};
#pragma unroll
        for (int nt = 0; nt < 6; ++nt)
#pragma unroll
            for (int r = 0; r < 4; ++r) {
                const int il = il0 + quad * 4 + r;
                const int w = nt * 16 + lm - il;
                const float v = (w >= 0 && w <= 64)
                    ? c[nt][r] * 0.17677669529663687f : -1e30f;
                c[nt][r] = v;
                mx[r] = fmaxf(mx[r], v);
            }
#pragma unroll
        for (int off = 1; off < 16; off <<= 1)
#pragma unroll
            for (int r = 0; r < 4; ++r) mx[r] = fmaxf(mx[r], __shfl_xor(mx[r], off, 64));
        float sm[4] = {0.f, 0.f, 0.f, 0.f};
#pragma unroll
        for (int nt = 0; nt < 6; ++nt)
#pragma unroll
            for (int r = 0; r < 4; ++r) {
                const int il = il0 + quad * 4 + r;
                const int w = nt * 16 + lm - il;
                const float e = (w >= 0 && w <= 64) ? __expf(c[nt][r] - mx[r]) : 0.f;
                c[nt][r] = e;
                sm[r] += e;
            }
#pragma unroll
        for (int off = 1; off < 16; off <<= 1)
#pragma unroll
            for (int r = 0; r < 4; ++r) sm[r] += __shfl_xor(sm[r], off, 64);
        float inv[4];
#pragma unroll
        for (int r = 0; r < 4; ++r) inv[r] = 1.f / sm[r];
#pragma unroll
        for (int nt = 0; nt < 6; ++nt)
#pragma unroll
            for (int r = 0; r < 4; ++r) {
                const int il = il0 + quad * 4 + r;
                const int jr = nt * 16 + lm;
                const int w = jr - il;
                if (w >= 0 && w <= 64) {
                    const float pw = c[nt][r] * inv[r];
                    attnw[((size_t)bh * Nn + (i0 + il)) * WL + w] = pw;
                    Pb[il * 104 + jr] = f2bf(pw);
                }
            }
    } else {
        // stage S^T (128 dims x 96 jr): V dims 0-31 (bf16), vec dims 32-127 (from fp32 x)
        const int tt = t - 128;
        const int chunk = tt >> 3, j0 = tt & 7;
#pragma unroll
        for (int it = 0; it < 12; ++it) {
            const int jr = j0 + it * 8;
            const int j = i0 - WIN + jr;
            bf16x8 val = {0, 0, 0, 0, 0, 0, 0, 0};
            if (j >= 0 && j < Nn) {
                if (chunk < 4) {
                    val = *(const bf16x8*)&Vb[((size_t)(b * Nn + j)) * 256 + hd * 32 + chunk * 8];
                } else {
                    const int vc = (chunk - 4) >> 2, d0 = ((chunk - 4) & 3) * 8;
                    const float* src = &x[((size_t)(b * Nn + j)) * 1024 + (1 + vc) * 256 + hd * 32 + d0];
                    val = cvt8(*(const float4*)src, *(const float4*)(src + 4));
                }
            }
#pragma unroll
            for (int u = 0; u < 8; ++u) St[(chunk * 8 + u) * 104 + jr] = val[u];
        }
    }
    __syncthreads();

    // phase 3: PV (32i x 128dim, K=96) + epilogue
    f32x4 acc[4];
#pragma unroll
    for (int nt = 0; nt < 4; ++nt) {
        f32x4 z = {0.f, 0.f, 0.f, 0.f};
        acc[nt] = z;
    }
#pragma unroll
    for (int ks = 0; ks < 3; ++ks) {
        const bf16x8 ap = *(bf16x8*)&Pb[(wm * 16 + lm) * 104 + ks * 32 + quad * 8];
#pragma unroll
        for (int nt = 0; nt < 4; ++nt) {
            const bf16x8 bs = *(bf16x8*)&St[(wn * 64 + nt * 16 + lm) * 104 + ks * 32 + quad * 8];
            acc[nt] = __builtin_amdgcn_mfma_f32_16x16x32_bf16(ap, bs, acc[nt], 0, 0, 0);
        }
    }
#pragma unroll
    for (int nt = 0; nt < 4; ++nt) {
        const int dim = wn * 64 + nt * 16 + lm;
#pragma unroll
        for (int r = 0; r < 4; ++r) {
            const int i = wm * 16 + quad * 4 + r;
            const size_t bn = (size_t)(b * Nn + i0 + i);
            if (dim < 32) {
                xout_bf[bn * 256 + hd * 32 + dim] = f2bf(acc[nt][r]);
            } else {
                const int dm = dim - 32, c = dm >> 5, dd = dm & 31;
                const int ch = hd * 32 + dd;
                const float g = gate[bn * 256 + ch];
                const size_t off = bn * 1024 + (1 + c) * 256 + ch;
                out[off] = fmaf(g, acc[nt][r], x[off]);
            }
        }
    }
}

// ---------------- output projection + scalar combine, pipelined ----------
__global__ __launch_bounds__(256) void gemm_outf(
    const short* __restrict__ A, const short* __restrict__ BT,
    const float* __restrict__ bo,
    const float* __restrict__ vec_dot, const float* __restrict__ vec_norm,
    float* __restrict__ out) {
    __shared__ short As[64 * 40];
    __shared__ short Bs[3][64 * 40];
    const int row0 = blockIdx.x * 64, ch0 = blockIdx.y * 64;
    const int t = threadIdx.x, lane = t & 63, wid = t >> 6;
    const int wm = wid & 1, wn = wid >> 1, quad = lane >> 4, lm = lane & 15;
    const int srow = t >> 2, scg = (t & 3) * 8;
    f32x4 acc[3][2][2];
#pragma unroll
    for (int p = 0; p < 3; ++p)
#pragma unroll
        for (int mt = 0; mt < 2; ++mt)
#pragma unroll
            for (int nt = 0; nt < 2; ++nt) {
                f32x4 z = {0.f, 0.f, 0.f, 0.f};
                acc[p][mt][nt] = z;
            }
    bf16x8 pa, pb[3];
    pa = *(const bf16x8*)&A[(size_t)(row0 + srow) * 256 + scg];
#pragma unroll
    for (int p = 0; p < 3; ++p)
        pb[p] = *(const bf16x8*)&BT[(size_t)(p * 256 + ch0 + srow) * 256 + scg];
    for (int k0 = 0; k0 < 256; k0 += 32) {
        *(bf16x8*)&As[srow * 40 + scg] = pa;
#pragma unroll
        for (int p = 0; p < 3; ++p)
            *(bf16x8*)&Bs[p][srow * 40 + scg] = pb[p];
        __syncthreads();
        if (k0 + 32 < 256) {
            pa = *(const bf16x8*)&A[(size_t)(row0 + srow) * 256 + k0 + 32 + scg];
#pragma unroll
            for (int p = 0; p < 3; ++p)
                pb[p] = *(const bf16x8*)&BT[(size_t)(p * 256 + ch0 + srow) * 256 + k0 + 32 + scg];
        }
        bf16x8 af[2], bfr[3][2];
#pragma unroll
        for (int mt = 0; mt < 2; ++mt)
            af[mt] = *(bf16x8*)&As[(wm * 32 + mt * 16 + lm) * 40 + quad * 8];
#pragma unroll
        for (int p = 0; p < 3; ++p)
#pragma unroll
            for (int nt = 0; nt < 2; ++nt)
                bfr[p][nt] = *(bf16x8*)&Bs[p][(wn * 32 + nt * 16 + lm) * 40 + quad * 8];
#pragma unroll
        for (int p = 0; p < 3; ++p)
#pragma unroll
            for (int mt = 0; mt < 2; ++mt)
#pragma unroll
                for (int nt = 0; nt < 2; ++nt)
                    acc[p][mt][nt] = __builtin_amdgcn_mfma_f32_16x16x32_bf16(
                        af[mt], bfr[p][nt], acc[p][mt][nt], 0, 0, 0);
        __syncthreads();
    }
#pragma unroll
    for (int mt = 0; mt < 2; ++mt)
#pragma unroll
        for (int nt = 0; nt < 2; ++nt) {
            const int col = ch0 + wn * 32 + nt * 16 + lm;
            const float b1 = bo[col], b2 = bo[256 + col], b3 = bo[512 + col];
#pragma unroll
            for (int r = 0; r < 4; ++r) {
                const int row = row0 + wm * 32 + mt * 16 + quad * 4 + r;
                const float o1 = acc[0][mt][nt][r] + b1;
                const float o2 = acc[1][mt][nt][r] + b2;
                const float o3 = acc[2][mt][nt][r] + b3;
                const float vd = vec_dot[(size_t)row * 256 + col];
                const float vn = vec_norm[(size_t)row * 256 + col];
                out[(size_t)row * 1024 + col] = vd * o1 + vn * o2 + o3;
            }
        }
}

extern "C" void kernel_launch(void* const* d_in, const int* in_sizes, int n_in,
                              void* d_out, int out_size, void* d_ws, size_t ws_size,
                              hipStream_t stream) {
    const float* x  = (const float*)d_in[0];
    const float* Wq = (const float*)d_in[1];
    const float* bq = (const float*)d_in[2];
    const float* Wk = (const float*)d_in[3];
    const float* bk = (const float*)d_in[4];
    const float* Wv = (const float*)d_in[5];
    const float* bv = (const float*)d_in[6];
    const float* Wo = (const float*)d_in[7];
    const float* bo = (const float*)d_in[8];
    const float* Wvec = (const float*)d_in[9];
    const float* alpha_dot  = (const float*)d_in[10];
    const float* alpha_norm = (const float*)d_in[11];
    const float* Wg = (const float*)d_in[12];
    const float* bg = (const float*)d_in[13];

    float* ws = (float*)d_ws;
    float* vec_dot  = ws;              // 1048576
    float* vec_norm = ws + 1048576;    // 1048576
    float* gate     = ws + 2097152;    // 1048576
    short* sb = (short*)(ws + 3145728);
    short* xout_bf = sb;               // 1048576
    short* Q_bf    = sb + 1048576;     // 1048576
    short* K_bf    = sb + 2097152;     // 1048576
    short* V_bf    = sb + 3145728;     // 1048576
    short* WqkvT   = sb + 4194304;     // 196608
    short* WvecT   = sb + 4390912;     // 131072
    short* WgT     = sb + 4521984;     // 131072
    short* WoT     = sb + 4653056;     // 196608

    float* out = (float*)d_out;
    float* attnw = out + (size_t)Bc * Nn * 4 * Hh;  // offset 4,194,304

    castw_kernel<<<640, 256, 0, stream>>>(Wq, Wk, Wv, Wvec, Wg, Wo,
                                          WqkvT, WvecT, WgT, WoT);
    fused_mid<<<640, 256, 0, stream>>>(x, WqkvT, WvecT, WgT, bq, bk, bv,
                                       alpha_dot, alpha_norm, bg,
                                       Q_bf, K_bf, V_bf, vec_dot, vec_norm, gate);
    attn_fused<<<1024, 256, 0, stream>>>(Q_bf, K_bf, V_bf, gate, x,
                                         attnw, out, xout_bf);
    gemm_outf<<<dim3(64, 4), 256, 0, stream>>>(xout_bf, WoT, bo, vec_dot, vec_norm, out);
}